// Round 1
// baseline (874.166 us; speedup 1.0000x reference)
//
#include <hip/hip_runtime.h>

// Problem constants
constexpr int L  = 384;   // pair/seq length
constexpr int R  = 256;   // MSA rows
constexpr int D  = 128;   // IN_DIM == PAIR_DIM
constexpr int NH = 8;     // heads
constexpr int HD = 16;    // head dim
constexpr int FF = 512;   // FF hidden

// ---------------------------------------------------------------------------
// Kernel 1: pair symmetrize + LN1 + logits (pair @ w1 + b1)
// one wave (64 lanes) per (i,j); each lane holds 2 of the 128 channels
// ---------------------------------------------------------------------------
__global__ void k_pair_logits(const float* __restrict__ x,
                              const float* __restrict__ g,
                              const float* __restrict__ bt,
                              const float* __restrict__ w1,
                              const float* __restrict__ b1,
                              float* __restrict__ logits) {
    const int wave = blockIdx.x * 4 + (threadIdx.x >> 6);
    const int lane = threadIdx.x & 63;
    const int i = wave / L, j = wave % L;

    const float2 a = *(const float2*)(x + ((size_t)i * L + j) * D + 2 * lane);
    const float2 b = *(const float2*)(x + ((size_t)j * L + i) * D + 2 * lane);
    float v0 = 0.5f * (a.x + b.x);
    float v1 = 0.5f * (a.y + b.y);

    float s = v0 + v1, sq = v0 * v0 + v1 * v1;
    #pragma unroll
    for (int msk = 32; msk; msk >>= 1) {
        s  += __shfl_xor(s, msk);
        sq += __shfl_xor(sq, msk);
    }
    const float mean = s * (1.0f / D);
    const float var  = sq * (1.0f / D) - mean * mean;
    const float rstd = rsqrtf(var + 1e-5f);

    const float n0 = (v0 - mean) * rstd * g[2 * lane]     + bt[2 * lane];
    const float n1 = (v1 - mean) * rstd * g[2 * lane + 1] + bt[2 * lane + 1];

    float outv = 0.0f;
    #pragma unroll
    for (int h = 0; h < NH; ++h) {
        float p = n0 * w1[(2 * lane) * NH + h] + n1 * w1[(2 * lane + 1) * NH + h];
        #pragma unroll
        for (int msk = 32; msk; msk >>= 1) p += __shfl_xor(p, msk);
        if (lane == h) outv = p;
    }
    if (lane < NH) logits[((size_t)i * L + j) * NH + lane] = outv + b1[lane];
}

// ---------------------------------------------------------------------------
// Kernel 2: softmax over j (axis=-2) for each (i,h); in place on logits
// one wave per (i,h); 384 = 6 * 64 elements per row
// ---------------------------------------------------------------------------
__global__ void k_softmax(float* __restrict__ logits) {
    const int wave = blockIdx.x * 4 + (threadIdx.x >> 6);
    const int lane = threadIdx.x & 63;
    const int i = wave / NH, h = wave % NH;

    float v[6];
    float mx = -1e30f;
    #pragma unroll
    for (int t = 0; t < 6; ++t) {
        const int j = lane + t * 64;
        v[t] = logits[((size_t)i * L + j) * NH + h];
        mx = fmaxf(mx, v[t]);
    }
    #pragma unroll
    for (int msk = 32; msk; msk >>= 1) mx = fmaxf(mx, __shfl_xor(mx, msk));

    float s = 0.0f;
    #pragma unroll
    for (int t = 0; t < 6; ++t) { v[t] = __expf(v[t] - mx); s += v[t]; }
    #pragma unroll
    for (int msk = 32; msk; msk >>= 1) s += __shfl_xor(s, msk);
    const float inv = 1.0f / s;

    #pragma unroll
    for (int t = 0; t < 6; ++t) {
        const int j = lane + t * 64;
        logits[((size_t)i * L + j) * NH + h] = v[t] * inv;
    }
}

// ---------------------------------------------------------------------------
// Kernel 3: values = LN2(m) @ w2 + b2, stored transposed: Vt[j][r*HD+d]
// one wave per (r,j)
// ---------------------------------------------------------------------------
__global__ void k_values(const float* __restrict__ min,
                         const float* __restrict__ g,
                         const float* __restrict__ bt,
                         const float* __restrict__ w2,
                         const float* __restrict__ b2,
                         float* __restrict__ Vt) {
    const int wave = blockIdx.x * 4 + (threadIdx.x >> 6);
    const int lane = threadIdx.x & 63;
    const int r = wave / L, j = wave % L;

    const float2 a = *(const float2*)(min + ((size_t)r * L + j) * D + 2 * lane);
    float v0 = a.x, v1 = a.y;

    float s = v0 + v1, sq = v0 * v0 + v1 * v1;
    #pragma unroll
    for (int msk = 32; msk; msk >>= 1) {
        s  += __shfl_xor(s, msk);
        sq += __shfl_xor(sq, msk);
    }
    const float mean = s * (1.0f / D);
    const float var  = sq * (1.0f / D) - mean * mean;
    const float rstd = rsqrtf(var + 1e-5f);

    const float n0 = (v0 - mean) * rstd * g[2 * lane]     + bt[2 * lane];
    const float n1 = (v1 - mean) * rstd * g[2 * lane + 1] + bt[2 * lane + 1];

    float outv = 0.0f;
    #pragma unroll
    for (int t = 0; t < HD; ++t) {
        float p = n0 * w2[(2 * lane) * HD + t] + n1 * w2[(2 * lane + 1) * HD + t];
        #pragma unroll
        for (int msk = 32; msk; msk >>= 1) p += __shfl_xor(p, msk);
        if (lane == t) outv = p;
    }
    if (lane < HD) Vt[((size_t)j * R + r) * HD + lane] = outv + b2[lane];
}

// ---------------------------------------------------------------------------
// Kernel 4: per-head GEMM: C[h][i, n] = sum_j attn[i,j,h] * Vt[j, n]
//           n = r*HD + d; epilogue: out[r,i,h*HD+d] = m[...] + C
// 64x64 tile, BK=16, 256 threads, 4x4 per thread
// ---------------------------------------------------------------------------
__global__ void k_attn_out(const float* __restrict__ attn,
                           const float* __restrict__ Vt,
                           const float* __restrict__ min,
                           float* __restrict__ out) {
    const int h  = blockIdx.z;
    const int i0 = blockIdx.x * 64;
    const int n0 = blockIdx.y * 64;

    __shared__ float As[16][64];
    __shared__ float Bs[16][64];

    const int tid = threadIdx.x;
    const int tx = tid & 15, ty = tid >> 4;

    float acc[4][4] = {};

    for (int k0 = 0; k0 < L; k0 += 16) {
        #pragma unroll
        for (int q = 0; q < 4; ++q) {
            const int idx = tid + q * 256;
            const int kk = idx & 15, mi = idx >> 4;
            As[kk][mi] = attn[((size_t)(i0 + mi) * L + k0 + kk) * NH + h];
        }
        #pragma unroll
        for (int q = 0; q < 4; ++q) {
            const int idx = tid + q * 256;
            const int ni = idx & 63, kk = idx >> 6;
            Bs[kk][ni] = Vt[(size_t)(k0 + kk) * (R * HD) + n0 + ni];
        }
        __syncthreads();

        #pragma unroll
        for (int kk = 0; kk < 16; ++kk) {
            float av[4], bv[4];
            #pragma unroll
            for (int q = 0; q < 4; ++q) av[q] = As[kk][ty * 4 + q];
            #pragma unroll
            for (int q = 0; q < 4; ++q) bv[q] = Bs[kk][tx * 4 + q];
            #pragma unroll
            for (int a = 0; a < 4; ++a)
                #pragma unroll
                for (int b = 0; b < 4; ++b) acc[a][b] += av[a] * bv[b];
        }
        __syncthreads();
    }

    #pragma unroll
    for (int a = 0; a < 4; ++a) {
        const int i = i0 + ty * 4 + a;
        #pragma unroll
        for (int b = 0; b < 4; ++b) {
            const int n = n0 + tx * 4 + b;
            const int r = n >> 4, d = n & 15;
            const size_t oi = ((size_t)r * L + i) * D + h * HD + d;
            out[oi] = min[oi] + acc[a][b];
        }
    }
}

// ---------------------------------------------------------------------------
// Kernel 5: fused LN3 + FFN + residual, in place on out. 8 rows per block.
// ---------------------------------------------------------------------------
__global__ void k_ff(const float* __restrict__ g3,
                     const float* __restrict__ bt3,
                     const float* __restrict__ ffw1,
                     const float* __restrict__ ffb1,
                     const float* __restrict__ ffw2,
                     const float* __restrict__ ffb2,
                     float* __restrict__ out) {
    __shared__ float res[8][D];
    __shared__ float orig[8][D];
    __shared__ float hid[8][FF];

    const size_t row0 = (size_t)blockIdx.x * 8;
    const int tid = threadIdx.x;

    // --- LN3 for 8 rows: 4 waves x 2 rows, 32 lanes per row, 4 elems each ---
    {
        const int wv = tid >> 6, lane = tid & 63;
        const int lrow = wv * 2 + (lane >> 5);
        const int l32  = lane & 31;
        const float4 mv = *(const float4*)(out + (row0 + lrow) * D + l32 * 4);
        float s  = mv.x + mv.y + mv.z + mv.w;
        float sq = mv.x * mv.x + mv.y * mv.y + mv.z * mv.z + mv.w * mv.w;
        #pragma unroll
        for (int msk = 16; msk; msk >>= 1) {
            s  += __shfl_xor(s, msk);
            sq += __shfl_xor(sq, msk);
        }
        const float mean = s * (1.0f / D);
        const float var  = sq * (1.0f / D) - mean * mean;
        const float rstd = rsqrtf(var + 1e-5f);
        *(float4*)(&orig[lrow][l32 * 4]) = mv;
        float4 rv;
        rv.x = (mv.x - mean) * rstd * g3[l32 * 4 + 0] + bt3[l32 * 4 + 0];
        rv.y = (mv.y - mean) * rstd * g3[l32 * 4 + 1] + bt3[l32 * 4 + 1];
        rv.z = (mv.z - mean) * rstd * g3[l32 * 4 + 2] + bt3[l32 * 4 + 2];
        rv.w = (mv.w - mean) * rstd * g3[l32 * 4 + 3] + bt3[l32 * 4 + 3];
        *(float4*)(&res[lrow][l32 * 4]) = rv;
    }
    __syncthreads();

    // --- stage 1: hidden = relu(res @ ffw1 + ffb1); thread t -> cols t, t+256
    {
        float acc0[8] = {}, acc1[8] = {};
        for (int k = 0; k < D; ++k) {
            const float w0 = ffw1[(size_t)k * FF + tid];
            const float w1v = ffw1[(size_t)k * FF + tid + 256];
            #pragma unroll
            for (int rr = 0; rr < 8; ++rr) {
                const float rk = res[rr][k];
                acc0[rr] += rk * w0;
                acc1[rr] += rk * w1v;
            }
        }
        const float bb0 = ffb1[tid], bb1 = ffb1[tid + 256];
        #pragma unroll
        for (int rr = 0; rr < 8; ++rr) {
            hid[rr][tid]       = fmaxf(acc0[rr] + bb0, 0.0f);
            hid[rr][tid + 256] = fmaxf(acc1[rr] + bb1, 0.0f);
        }
    }
    __syncthreads();

    // --- stage 2: final = hidden @ ffw2 + ffb2; residual add, in-place ---
    {
        const int c  = tid & 127;
        const int rb = (tid >> 7) * 4;
        float acc[4] = {};
        for (int k = 0; k < FF; ++k) {
            const float w = ffw2[(size_t)k * D + c];
            #pragma unroll
            for (int rr = 0; rr < 4; ++rr) acc[rr] += hid[rb + rr][k] * w;
        }
        const float bb = ffb2[c];
        #pragma unroll
        for (int rr = 0; rr < 4; ++rr) {
            out[(row0 + rb + rr) * D + c] = orig[rb + rr][c] + acc[rr] + bb;
        }
    }
}

// ---------------------------------------------------------------------------
extern "C" void kernel_launch(void* const* d_in, const int* in_sizes, int n_in,
                              void* d_out, int out_size, void* d_ws, size_t ws_size,
                              hipStream_t stream) {
    const float* x     = (const float*)d_in[0];
    const float* m     = (const float*)d_in[1];
    const float* ln1_g = (const float*)d_in[2];
    const float* ln1_b = (const float*)d_in[3];
    const float* ln2_g = (const float*)d_in[4];
    const float* ln2_b = (const float*)d_in[5];
    const float* ln3_g = (const float*)d_in[6];
    const float* ln3_b = (const float*)d_in[7];
    const float* w1    = (const float*)d_in[8];
    const float* b1    = (const float*)d_in[9];
    const float* w2    = (const float*)d_in[10];
    const float* b2    = (const float*)d_in[11];
    const float* ffw1  = (const float*)d_in[12];
    const float* ffb1  = (const float*)d_in[13];
    const float* ffw2  = (const float*)d_in[14];
    const float* ffb2  = (const float*)d_in[15];

    float* out  = (float*)d_out;
    float* attn = (float*)d_ws;                      // [L, L, NH]   = 4.72 MB
    float* Vt   = attn + (size_t)L * L * NH;         // [L, R*HD]    = 6.29 MB

    k_pair_logits<<<L * L / 4, 256, 0, stream>>>(x, ln1_g, ln1_b, w1, b1, attn);
    k_softmax<<<L * NH / 4, 256, 0, stream>>>(attn);
    k_values<<<R * L / 4, 256, 0, stream>>>(m, ln2_g, ln2_b, w2, b2, Vt);

    dim3 g4(L / 64, (R * HD) / 64, NH);
    k_attn_out<<<g4, 256, 0, stream>>>(attn, Vt, m, out);

    k_ff<<<R * L / 8, 256, 0, stream>>>(ln3_g, ln3_b, ffw1, ffb1, ffw2, ffb2, out);
}

// Round 2
// 322.596 us; speedup vs baseline: 2.7098x; 2.7098x over previous
//
#include <hip/hip_runtime.h>

typedef __attribute__((ext_vector_type(8))) short bf16x8;
typedef __attribute__((ext_vector_type(4))) float f32x4;

constexpr int L  = 384;
constexpr int R  = 256;
constexpr int D  = 128;
constexpr int NH = 8;
constexpr int HD = 16;
constexpr int FF = 512;

#define MFMA16(a, b, c) __builtin_amdgcn_mfma_f32_16x16x32_bf16((a), (b), (c), 0, 0, 0)

__device__ inline unsigned short f2bf(float f) {
    unsigned u = __builtin_bit_cast(unsigned, f);
    u += 0x7fffu + ((u >> 16) & 1u);          // round-to-nearest-even
    return (unsigned short)(u >> 16);
}

// ---------------------------------------------------------------------------
// Prep: bf16-transposed weight copies in workspace.
//   w1t[n][k] = ffw1[k][n]   (512 x 128)
//   w2t[n][k] = ffw2[k][n]   (128 x 512)
//   w1p[n][k] = w1[k][n] zero-padded to 16 heads  (16 x 128)
// ---------------------------------------------------------------------------
__global__ void k_prep(const float* __restrict__ w1,
                       const float* __restrict__ ffw1,
                       const float* __restrict__ ffw2,
                       unsigned short* __restrict__ w1p,
                       unsigned short* __restrict__ w1t,
                       unsigned short* __restrict__ w2t) {
    const int idx = blockIdx.x * 256 + threadIdx.x;   // 65536 threads
    { const int n = idx >> 7, k = idx & 127; w1t[idx] = f2bf(ffw1[(size_t)k * FF + n]); }
    { const int n = idx >> 9, k = idx & 511; w2t[idx] = f2bf(ffw2[(size_t)k * D + n]); }
    if (idx < 16 * D) {
        const int n = idx >> 7, k = idx & 127;
        w1p[idx] = (n < NH) ? f2bf(w1[(size_t)k * NH + n]) : (unsigned short)0;
    }
}

// ---------------------------------------------------------------------------
// Kernel 1: symmetrize + LN1 + logits via MFMA. 64 (i,j) pairs per block.
// ---------------------------------------------------------------------------
__global__ void k_pair_logits(const float* __restrict__ x,
                              const float* __restrict__ g,
                              const float* __restrict__ bt,
                              const unsigned short* __restrict__ w1p,
                              const float* __restrict__ b1,
                              float* __restrict__ logits) {
    __shared__ unsigned short nrm[64][136];
    const int tid = threadIdx.x;
    const int p0 = blockIdx.x * 64;

    // Phase A: LN over 128 channels; 4 threads per pair, 32 channels each
    {
        const int pr = tid >> 2, part = tid & 3;
        const int p = p0 + pr;
        const int i = p / L, j = p % L;
        const float* xa = x + ((size_t)i * L + j) * D + part * 32;
        const float* xb = x + ((size_t)j * L + i) * D + part * 32;
        float v[32];
        float s = 0.f, sq = 0.f;
        #pragma unroll
        for (int q = 0; q < 8; ++q) {
            const float4 a = ((const float4*)xa)[q];
            const float4 b = ((const float4*)xb)[q];
            const float t0 = 0.5f * (a.x + b.x), t1 = 0.5f * (a.y + b.y);
            const float t2 = 0.5f * (a.z + b.z), t3 = 0.5f * (a.w + b.w);
            v[q*4+0] = t0; v[q*4+1] = t1; v[q*4+2] = t2; v[q*4+3] = t3;
            s  += t0 + t1 + t2 + t3;
            sq += t0*t0 + t1*t1 + t2*t2 + t3*t3;
        }
        s  += __shfl_xor(s, 1);  s  += __shfl_xor(s, 2);
        sq += __shfl_xor(sq, 1); sq += __shfl_xor(sq, 2);
        const float mean = s * (1.0f / D);
        const float rstd = rsqrtf(sq * (1.0f / D) - mean * mean + 1e-5f);
        #pragma unroll
        for (int e = 0; e < 32; ++e) {
            const int c = part * 32 + e;
            nrm[pr][c] = f2bf((v[e] - mean) * rstd * g[c] + bt[c]);
        }
    }
    __syncthreads();

    // Phase B: logits = nrm @ w1 via MFMA (one 16x16 tile per wave, 4 K-steps)
    {
        const int wv = tid >> 6, lane = tid & 63;
        const int lr = lane & 15, lg = lane >> 4;
        f32x4 acc = {0.f, 0.f, 0.f, 0.f};
        #pragma unroll
        for (int ks = 0; ks < 4; ++ks) {
            bf16x8 a = *(const bf16x8*)(&nrm[wv * 16 + lr][ks * 32 + lg * 8]);
            bf16x8 b = *(const bf16x8*)(w1p + (size_t)lr * D + ks * 32 + lg * 8);
            acc = MFMA16(a, b, acc);
        }
        if (lr < NH) {
            #pragma unroll
            for (int r = 0; r < 4; ++r) {
                const int pl = wv * 16 + lg * 4 + r;
                logits[(size_t)(p0 + pl) * NH + lr] = acc[r] + b1[lr];
            }
        }
    }
}

// ---------------------------------------------------------------------------
// Kernel 2: softmax over j for each (i,h); logits f32 -> attnT bf16 [h][i][j]
// ---------------------------------------------------------------------------
__global__ void k_softmax(const float* __restrict__ logits,
                          unsigned short* __restrict__ attnT) {
    const int wave = blockIdx.x * 4 + (threadIdx.x >> 6);
    const int lane = threadIdx.x & 63;
    const int i = wave >> 3, h = wave & 7;

    float v[6];
    float mx = -1e30f;
    #pragma unroll
    for (int t = 0; t < 6; ++t) {
        const int j = lane + t * 64;
        v[t] = logits[((size_t)i * L + j) * NH + h];
        mx = fmaxf(mx, v[t]);
    }
    #pragma unroll
    for (int msk = 32; msk; msk >>= 1) mx = fmaxf(mx, __shfl_xor(mx, msk));

    float s = 0.0f;
    #pragma unroll
    for (int t = 0; t < 6; ++t) { v[t] = __expf(v[t] - mx); s += v[t]; }
    #pragma unroll
    for (int msk = 32; msk; msk >>= 1) s += __shfl_xor(s, msk);
    const float inv = 1.0f / s;

    #pragma unroll
    for (int t = 0; t < 6; ++t) {
        const int j = lane + t * 64;
        attnT[((size_t)h * L + i) * L + j] = f2bf(v[t] * inv);
    }
}

// ---------------------------------------------------------------------------
// Kernel 3: values = LN2(m) @ w2 + b2 -> VtT bf16 [n = r*16+d][j]
// one wave per (r,j)
// ---------------------------------------------------------------------------
__global__ void k_values(const float* __restrict__ min_,
                         const float* __restrict__ g,
                         const float* __restrict__ bt,
                         const float* __restrict__ w2,
                         const float* __restrict__ b2,
                         unsigned short* __restrict__ VtT) {
    const int wave = blockIdx.x * 4 + (threadIdx.x >> 6);
    const int lane = threadIdx.x & 63;
    const int r = wave / L, j = wave % L;

    const float2 a = *(const float2*)(min_ + ((size_t)r * L + j) * D + 2 * lane);
    float v0 = a.x, v1 = a.y;

    float s = v0 + v1, sq = v0 * v0 + v1 * v1;
    #pragma unroll
    for (int msk = 32; msk; msk >>= 1) {
        s  += __shfl_xor(s, msk);
        sq += __shfl_xor(sq, msk);
    }
    const float mean = s * (1.0f / D);
    const float var  = sq * (1.0f / D) - mean * mean;
    const float rstd = rsqrtf(var + 1e-5f);

    const float n0 = (v0 - mean) * rstd * g[2 * lane]     + bt[2 * lane];
    const float n1 = (v1 - mean) * rstd * g[2 * lane + 1] + bt[2 * lane + 1];

    float outv = 0.0f;
    #pragma unroll
    for (int t = 0; t < HD; ++t) {
        float p = n0 * w2[(2 * lane) * HD + t] + n1 * w2[(2 * lane + 1) * HD + t];
        #pragma unroll
        for (int msk = 32; msk; msk >>= 1) p += __shfl_xor(p, msk);
        if (lane == t) outv = p;
    }
    if (lane < HD) VtT[(size_t)(r * HD + lane) * L + j] = f2bf(outv + b2[lane]);
}

// ---------------------------------------------------------------------------
// Kernel 4: einsum via MFMA. Per head: C[i,n] = sum_j attnT[h][i][j]*VtT[n][j]
// 128(i) x 128(n) block tile, 4 waves (2x2 of 64x64), K=384 in 12 steps.
// Fragments straight from global (L2-resident). Epilogue adds residual m.
// ---------------------------------------------------------------------------
__global__ void k_attn_out(const unsigned short* __restrict__ attnT,
                           const unsigned short* __restrict__ VtT,
                           const float* __restrict__ min_,
                           float* __restrict__ out) {
    const int h  = blockIdx.z;
    const int i0 = blockIdx.x * 128;
    const int n0 = blockIdx.y * 128;
    const int tid = threadIdx.x, wv = tid >> 6, lane = tid & 63;
    const int lr = lane & 15, lg = lane >> 4;
    const int wio = (wv >> 1) * 64, wno = (wv & 1) * 64;
    const unsigned short* Abase = attnT + (size_t)h * L * L;

    f32x4 acc[4][4];
    #pragma unroll
    for (int a = 0; a < 4; ++a)
        #pragma unroll
        for (int b = 0; b < 4; ++b) acc[a][b] = (f32x4){0.f, 0.f, 0.f, 0.f};

    for (int ks = 0; ks < 12; ++ks) {
        bf16x8 af[4], bf[4];
        #pragma unroll
        for (int mt = 0; mt < 4; ++mt)
            af[mt] = *(const bf16x8*)(Abase + (size_t)(i0 + wio + mt * 16 + lr) * L + ks * 32 + lg * 8);
        #pragma unroll
        for (int nt = 0; nt < 4; ++nt)
            bf[nt] = *(const bf16x8*)(VtT + (size_t)(n0 + wno + nt * 16 + lr) * L + ks * 32 + lg * 8);
        #pragma unroll
        for (int mt = 0; mt < 4; ++mt)
            #pragma unroll
            for (int nt = 0; nt < 4; ++nt)
                acc[mt][nt] = MFMA16(af[mt], bf[nt], acc[mt][nt]);
    }

    #pragma unroll
    for (int mt = 0; mt < 4; ++mt) {
        #pragma unroll
        for (int nt = 0; nt < 4; ++nt) {
            const int nbase = n0 + wno + nt * 16;   // multiple of 16
            const int rrow  = nbase >> 4;
            #pragma unroll
            for (int r = 0; r < 4; ++r) {
                const int i = i0 + wio + mt * 16 + lg * 4 + r;
                const size_t gidx = ((size_t)rrow * L + i) * D + h * HD + lr;
                out[gidx] = min_[gidx] + acc[mt][nt][r];
            }
        }
    }
}

// ---------------------------------------------------------------------------
// Kernel 5: fused LN3 + FFN (MFMA) + residual, in place on out. 32 rows/block.
// ---------------------------------------------------------------------------
__global__ void k_ffn(const float* __restrict__ g3,
                      const float* __restrict__ bt3,
                      const unsigned short* __restrict__ w1t,
                      const float* __restrict__ ffb1,
                      const unsigned short* __restrict__ w2t,
                      const float* __restrict__ ffb2,
                      float* __restrict__ out) {
    __shared__ unsigned short resN[32][136];
    __shared__ unsigned short hid[32][520];
    const int tid = threadIdx.x;
    const size_t row0 = (size_t)blockIdx.x * 32;

    // Phase A: LN3, 8 threads per row x 16 channels
    {
        const int rr = tid >> 3, part = tid & 7;
        const float* src = out + (row0 + rr) * D + part * 16;
        float v[16];
        float s = 0.f, sq = 0.f;
        #pragma unroll
        for (int q = 0; q < 4; ++q) {
            const float4 a = ((const float4*)src)[q];
            v[q*4+0] = a.x; v[q*4+1] = a.y; v[q*4+2] = a.z; v[q*4+3] = a.w;
            s  += a.x + a.y + a.z + a.w;
            sq += a.x*a.x + a.y*a.y + a.z*a.z + a.w*a.w;
        }
        s  += __shfl_xor(s, 1);  s  += __shfl_xor(s, 2);  s  += __shfl_xor(s, 4);
        sq += __shfl_xor(sq, 1); sq += __shfl_xor(sq, 2); sq += __shfl_xor(sq, 4);
        const float mean = s * (1.0f / D);
        const float rstd = rsqrtf(sq * (1.0f / D) - mean * mean + 1e-5f);
        #pragma unroll
        for (int e = 0; e < 16; ++e) {
            const int c = part * 16 + e;
            resN[rr][c] = f2bf((v[e] - mean) * rstd * g3[c] + bt3[c]);
        }
    }
    __syncthreads();

    const int wv = tid >> 6, lane = tid & 63;
    const int lr = lane & 15, lg = lane >> 4;

    // Phase B: hid = relu(resN @ w1t^T + ffb1); wave handles 128 hidden cols
    {
        f32x4 acc[2][8];
        #pragma unroll
        for (int m = 0; m < 2; ++m)
            #pragma unroll
            for (int n = 0; n < 8; ++n) acc[m][n] = (f32x4){0.f, 0.f, 0.f, 0.f};

        #pragma unroll
        for (int ks = 0; ks < 4; ++ks) {
            bf16x8 a0 = *(const bf16x8*)(&resN[lr][ks * 32 + lg * 8]);
            bf16x8 a1 = *(const bf16x8*)(&resN[16 + lr][ks * 32 + lg * 8]);
            #pragma unroll
            for (int nt = 0; nt < 8; ++nt) {
                const unsigned short* bp = w1t + (size_t)(wv * 128 + nt * 16 + lr) * D + ks * 32 + lg * 8;
                bf16x8 b = *(const bf16x8*)bp;
                acc[0][nt] = MFMA16(a0, b, acc[0][nt]);
                acc[1][nt] = MFMA16(a1, b, acc[1][nt]);
            }
        }
        #pragma unroll
        for (int m = 0; m < 2; ++m) {
            #pragma unroll
            for (int nt = 0; nt < 8; ++nt) {
                const int colg = wv * 128 + nt * 16 + lr;
                const float bb = ffb1[colg];
                #pragma unroll
                for (int r = 0; r < 4; ++r) {
                    hid[m * 16 + lg * 4 + r][colg] = f2bf(fmaxf(acc[m][nt][r] + bb, 0.f));
                }
            }
        }
    }
    __syncthreads();

    // Phase C: final = hid @ w2t^T + ffb2 + residual; wave handles 32 cols
    {
        f32x4 acc2[2][2];
        #pragma unroll
        for (int m = 0; m < 2; ++m)
            #pragma unroll
            for (int n = 0; n < 2; ++n) acc2[m][n] = (f32x4){0.f, 0.f, 0.f, 0.f};

        #pragma unroll
        for (int ks = 0; ks < 16; ++ks) {
            bf16x8 a0 = *(const bf16x8*)(&hid[lr][ks * 32 + lg * 8]);
            bf16x8 a1 = *(const bf16x8*)(&hid[16 + lr][ks * 32 + lg * 8]);
            #pragma unroll
            for (int nt = 0; nt < 2; ++nt) {
                const unsigned short* bp = w2t + (size_t)(wv * 32 + nt * 16 + lr) * FF + ks * 32 + lg * 8;
                bf16x8 b = *(const bf16x8*)bp;
                acc2[0][nt] = MFMA16(a0, b, acc2[0][nt]);
                acc2[1][nt] = MFMA16(a1, b, acc2[1][nt]);
            }
        }
        #pragma unroll
        for (int m = 0; m < 2; ++m) {
            #pragma unroll
            for (int nt = 0; nt < 2; ++nt) {
                const int n = wv * 32 + nt * 16 + lr;
                const float bb = ffb2[n];
                #pragma unroll
                for (int r = 0; r < 4; ++r) {
                    const size_t gi = (row0 + m * 16 + lg * 4 + r) * (size_t)D + n;
                    out[gi] = out[gi] + acc2[m][nt][r] + bb;
                }
            }
        }
    }
}

// ---------------------------------------------------------------------------
extern "C" void kernel_launch(void* const* d_in, const int* in_sizes, int n_in,
                              void* d_out, int out_size, void* d_ws, size_t ws_size,
                              hipStream_t stream) {
    const float* x     = (const float*)d_in[0];
    const float* m     = (const float*)d_in[1];
    const float* ln1_g = (const float*)d_in[2];
    const float* ln1_b = (const float*)d_in[3];
    const float* ln2_g = (const float*)d_in[4];
    const float* ln2_b = (const float*)d_in[5];
    const float* ln3_g = (const float*)d_in[6];
    const float* ln3_b = (const float*)d_in[7];
    const float* w1    = (const float*)d_in[8];
    const float* b1    = (const float*)d_in[9];
    const float* w2    = (const float*)d_in[10];
    const float* b2    = (const float*)d_in[11];
    const float* ffw1  = (const float*)d_in[12];
    const float* ffb1  = (const float*)d_in[13];
    const float* ffw2  = (const float*)d_in[14];
    const float* ffb2  = (const float*)d_in[15];

    float* out = (float*)d_out;

    float*          logits = (float*)d_ws;                         // 4.72 MB
    unsigned short* attnT  = (unsigned short*)(logits + (size_t)L * L * NH); // 2.36 MB
    unsigned short* VtT    = attnT + (size_t)NH * L * L;           // 3.15 MB
    unsigned short* w1t    = VtT + (size_t)R * HD * L;             // 128 KB
    unsigned short* w2t    = w1t + (size_t)FF * D;                 // 128 KB
    unsigned short* w1p    = w2t + (size_t)D * FF;                 // 4 KB

    k_prep<<<(FF * D) / 256, 256, 0, stream>>>(w1, ffw1, ffw2, w1p, w1t, w2t);
    k_pair_logits<<<(L * L) / 64, 256, 0, stream>>>(x, ln1_g, ln1_b, w1p, b1, logits);
    k_softmax<<<(L * NH) / 4, 256, 0, stream>>>(logits, attnT);
    k_values<<<(R * L) / 4, 256, 0, stream>>>(m, ln2_g, ln2_b, w2, b2, VtT);

    dim3 g4(L / 128, (R * HD) / 128, NH);
    k_attn_out<<<g4, 256, 0, stream>>>(attnT, VtT, m, out);

    k_ffn<<<(R * L) / 32, 256, 0, stream>>>(ln3_g, ln3_b, w1t, ffb1, w2t, ffb2, out);
}

// Round 3
// 232.192 us; speedup vs baseline: 3.7648x; 1.3893x over previous
//
#include <hip/hip_runtime.h>

typedef __attribute__((ext_vector_type(8))) short bf16x8;
typedef __attribute__((ext_vector_type(4))) float f32x4;

constexpr int L  = 384;
constexpr int R  = 256;
constexpr int D  = 128;
constexpr int NH = 8;
constexpr int HD = 16;
constexpr int FF = 512;

#define MFMA16(a, b, c) __builtin_amdgcn_mfma_f32_16x16x32_bf16((a), (b), (c), 0, 0, 0)

__device__ inline unsigned short f2bf(float f) {
    unsigned u = __builtin_bit_cast(unsigned, f);
    u += 0x7fffu + ((u >> 16) & 1u);          // round-to-nearest-even
    return (unsigned short)(u >> 16);
}

// ---------------------------------------------------------------------------
// Prep: bf16-transposed weight copies in workspace.
//   w1t[n][k] = ffw1[k][n]   (512 x 128)
//   w2t[n][k] = ffw2[k][n]   (128 x 512)
//   w1p[n][k] = w1[k][n] zero-padded to 16 heads  (16 x 128)
//   w2p[d][k] = w2[k][d]                          (16 x 128)
// ---------------------------------------------------------------------------
__global__ void k_prep(const float* __restrict__ w1,
                       const float* __restrict__ w2,
                       const float* __restrict__ ffw1,
                       const float* __restrict__ ffw2,
                       unsigned short* __restrict__ w1p,
                       unsigned short* __restrict__ w2p,
                       unsigned short* __restrict__ w1t,
                       unsigned short* __restrict__ w2t) {
    const int idx = blockIdx.x * 256 + threadIdx.x;   // 65536 threads
    { const int n = idx >> 7, k = idx & 127; w1t[idx] = f2bf(ffw1[(size_t)k * FF + n]); }
    { const int n = idx >> 9, k = idx & 511; w2t[idx] = f2bf(ffw2[(size_t)k * D + n]); }
    if (idx < 16 * D) {
        const int n = idx >> 7, k = idx & 127;
        w1p[idx] = (n < NH) ? f2bf(w1[(size_t)k * NH + n]) : (unsigned short)0;
        w2p[idx] = f2bf(w2[(size_t)k * HD + n]);
    }
}

// ---------------------------------------------------------------------------
// Kernel 1: symmetrize + LN1 + logits via MFMA. 64 (i,j) pairs per block.
// ---------------------------------------------------------------------------
__global__ void k_pair_logits(const float* __restrict__ x,
                              const float* __restrict__ g,
                              const float* __restrict__ bt,
                              const unsigned short* __restrict__ w1p,
                              const float* __restrict__ b1,
                              float* __restrict__ logits) {
    __shared__ unsigned short nrm[64][136];
    const int tid = threadIdx.x;
    const int p0 = blockIdx.x * 64;

    // Phase A: LN over 128 channels; 4 threads per pair, 32 channels each
    {
        const int pr = tid >> 2, part = tid & 3;
        const int p = p0 + pr;
        const int i = p / L, j = p % L;
        const float* xa = x + ((size_t)i * L + j) * D + part * 32;
        const float* xb = x + ((size_t)j * L + i) * D + part * 32;
        float v[32];
        float s = 0.f, sq = 0.f;
        #pragma unroll
        for (int q = 0; q < 8; ++q) {
            const float4 a = ((const float4*)xa)[q];
            const float4 b = ((const float4*)xb)[q];
            const float t0 = 0.5f * (a.x + b.x), t1 = 0.5f * (a.y + b.y);
            const float t2 = 0.5f * (a.z + b.z), t3 = 0.5f * (a.w + b.w);
            v[q*4+0] = t0; v[q*4+1] = t1; v[q*4+2] = t2; v[q*4+3] = t3;
            s  += t0 + t1 + t2 + t3;
            sq += t0*t0 + t1*t1 + t2*t2 + t3*t3;
        }
        s  += __shfl_xor(s, 1);  s  += __shfl_xor(s, 2);
        sq += __shfl_xor(sq, 1); sq += __shfl_xor(sq, 2);
        const float mean = s * (1.0f / D);
        const float rstd = rsqrtf(sq * (1.0f / D) - mean * mean + 1e-5f);
        #pragma unroll
        for (int q = 0; q < 8; ++q) {
            const int c = part * 32 + q * 4;
            ushort4 pk;
            pk.x = f2bf((v[q*4+0] - mean) * rstd * g[c+0] + bt[c+0]);
            pk.y = f2bf((v[q*4+1] - mean) * rstd * g[c+1] + bt[c+1]);
            pk.z = f2bf((v[q*4+2] - mean) * rstd * g[c+2] + bt[c+2]);
            pk.w = f2bf((v[q*4+3] - mean) * rstd * g[c+3] + bt[c+3]);
            *(ushort4*)(&nrm[pr][c]) = pk;
        }
    }
    __syncthreads();

    // Phase B: logits = nrm @ w1 via MFMA (one 16x16 tile per wave, 4 K-steps)
    {
        const int wv = tid >> 6, lane = tid & 63;
        const int lr = lane & 15, lg = lane >> 4;
        f32x4 acc = {0.f, 0.f, 0.f, 0.f};
        #pragma unroll
        for (int ks = 0; ks < 4; ++ks) {
            bf16x8 a = *(const bf16x8*)(&nrm[wv * 16 + lr][ks * 32 + lg * 8]);
            bf16x8 b = *(const bf16x8*)(w1p + (size_t)lr * D + ks * 32 + lg * 8);
            acc = MFMA16(a, b, acc);
        }
        if (lr < NH) {
            #pragma unroll
            for (int r = 0; r < 4; ++r) {
                const int pl = wv * 16 + lg * 4 + r;
                logits[(size_t)(p0 + pl) * NH + lr] = acc[r] + b1[lr];
            }
        }
    }
}

// ---------------------------------------------------------------------------
// Kernel 2: softmax over j for each (i,h); logits f32 -> attnT bf16 [h][i][j]
// ---------------------------------------------------------------------------
__global__ void k_softmax(const float* __restrict__ logits,
                          unsigned short* __restrict__ attnT) {
    const int wave = blockIdx.x * 4 + (threadIdx.x >> 6);
    const int lane = threadIdx.x & 63;
    const int i = wave >> 3, h = wave & 7;

    float v[6];
    float mx = -1e30f;
    #pragma unroll
    for (int t = 0; t < 6; ++t) {
        const int j = lane + t * 64;
        v[t] = logits[((size_t)i * L + j) * NH + h];
        mx = fmaxf(mx, v[t]);
    }
    #pragma unroll
    for (int msk = 32; msk; msk >>= 1) mx = fmaxf(mx, __shfl_xor(mx, msk));

    float s = 0.0f;
    #pragma unroll
    for (int t = 0; t < 6; ++t) { v[t] = __expf(v[t] - mx); s += v[t]; }
    #pragma unroll
    for (int msk = 32; msk; msk >>= 1) s += __shfl_xor(s, msk);
    const float inv = 1.0f / s;

    #pragma unroll
    for (int t = 0; t < 6; ++t) {
        const int j = lane + t * 64;
        attnT[((size_t)h * L + i) * L + j] = f2bf(v[t] * inv);
    }
}

// ---------------------------------------------------------------------------
// Kernel 3: values = LN2(m) @ w2 + b2 -> VtT bf16 [n = r*16+d][j]
// One block per (r, 128 j's): LN -> LDS bf16 -> MFMA vs w2p[16][128].
// ---------------------------------------------------------------------------
__global__ void k_values(const float* __restrict__ min_,
                         const float* __restrict__ g,
                         const float* __restrict__ bt,
                         const unsigned short* __restrict__ w2p,
                         const float* __restrict__ b2,
                         unsigned short* __restrict__ VtT) {
    __shared__ unsigned short nrm[128][136];
    const int tid = threadIdx.x;
    const int r  = blockIdx.x;
    const int j0 = blockIdx.y * 128;

    // Phase A: LN2 for 128 rows; 4 threads/row, 32 ch each; two passes
    #pragma unroll
    for (int half = 0; half < 2; ++half) {
        const int row  = half * 64 + (tid >> 2);
        const int part = tid & 3;
        const float* src = min_ + ((size_t)r * L + j0 + row) * D + part * 32;
        float v[32];
        float s = 0.f, sq = 0.f;
        #pragma unroll
        for (int q = 0; q < 8; ++q) {
            const float4 a = ((const float4*)src)[q];
            v[q*4+0] = a.x; v[q*4+1] = a.y; v[q*4+2] = a.z; v[q*4+3] = a.w;
            s  += a.x + a.y + a.z + a.w;
            sq += a.x*a.x + a.y*a.y + a.z*a.z + a.w*a.w;
        }
        s  += __shfl_xor(s, 1);  s  += __shfl_xor(s, 2);
        sq += __shfl_xor(sq, 1); sq += __shfl_xor(sq, 2);
        const float mean = s * (1.0f / D);
        const float rstd = rsqrtf(sq * (1.0f / D) - mean * mean + 1e-5f);
        #pragma unroll
        for (int q = 0; q < 8; ++q) {
            const int c = part * 32 + q * 4;
            ushort4 pk;
            pk.x = f2bf((v[q*4+0] - mean) * rstd * g[c+0] + bt[c+0]);
            pk.y = f2bf((v[q*4+1] - mean) * rstd * g[c+1] + bt[c+1]);
            pk.z = f2bf((v[q*4+2] - mean) * rstd * g[c+2] + bt[c+2]);
            pk.w = f2bf((v[q*4+3] - mean) * rstd * g[c+3] + bt[c+3]);
            *(ushort4*)(&nrm[row][c]) = pk;
        }
    }
    __syncthreads();

    // Phase B: C[j][d] = nrm @ w2p^T; wave handles 32 j's (2 tiles of 16)
    {
        const int wv = tid >> 6, lane = tid & 63;
        const int lr = lane & 15, lg = lane >> 4;
        f32x4 acc[2];
        acc[0] = (f32x4){0.f, 0.f, 0.f, 0.f};
        acc[1] = (f32x4){0.f, 0.f, 0.f, 0.f};
        #pragma unroll
        for (int ks = 0; ks < 4; ++ks) {
            bf16x8 b = *(const bf16x8*)(w2p + (size_t)lr * D + ks * 32 + lg * 8);
            #pragma unroll
            for (int mt = 0; mt < 2; ++mt) {
                bf16x8 a = *(const bf16x8*)(&nrm[wv * 32 + mt * 16 + lr][ks * 32 + lg * 8]);
                acc[mt] = MFMA16(a, b, acc[mt]);
            }
        }
        const float bb = b2[lr];
        #pragma unroll
        for (int mt = 0; mt < 2; ++mt) {
            ushort4 pk;
            pk.x = f2bf(acc[mt][0] + bb);
            pk.y = f2bf(acc[mt][1] + bb);
            pk.z = f2bf(acc[mt][2] + bb);
            pk.w = f2bf(acc[mt][3] + bb);
            *(ushort4*)(VtT + (size_t)(r * HD + lr) * L + j0 + wv * 32 + mt * 16 + lg * 4) = pk;
        }
    }
}

// ---------------------------------------------------------------------------
// Kernel 4: einsum via MFMA. Per head: C[i,n] = sum_j attnT[h][i][j]*VtT[n][j]
// 128(i) x 128(n) block tile, 4 waves (2x2 of 64x64), K=384 in 12 steps.
// Fragments straight from global (L2-resident). Epilogue adds residual m.
// ---------------------------------------------------------------------------
__global__ void k_attn_out(const unsigned short* __restrict__ attnT,
                           const unsigned short* __restrict__ VtT,
                           const float* __restrict__ min_,
                           float* __restrict__ out) {
    const int h  = blockIdx.z;
    const int i0 = blockIdx.x * 128;
    const int n0 = blockIdx.y * 128;
    const int tid = threadIdx.x, wv = tid >> 6, lane = tid & 63;
    const int lr = lane & 15, lg = lane >> 4;
    const int wio = (wv >> 1) * 64, wno = (wv & 1) * 64;
    const unsigned short* Abase = attnT + (size_t)h * L * L;

    f32x4 acc[4][4];
    #pragma unroll
    for (int a = 0; a < 4; ++a)
        #pragma unroll
        for (int b = 0; b < 4; ++b) acc[a][b] = (f32x4){0.f, 0.f, 0.f, 0.f};

    for (int ks = 0; ks < 12; ++ks) {
        bf16x8 af[4], bf[4];
        #pragma unroll
        for (int mt = 0; mt < 4; ++mt)
            af[mt] = *(const bf16x8*)(Abase + (size_t)(i0 + wio + mt * 16 + lr) * L + ks * 32 + lg * 8);
        #pragma unroll
        for (int nt = 0; nt < 4; ++nt)
            bf[nt] = *(const bf16x8*)(VtT + (size_t)(n0 + wno + nt * 16 + lr) * L + ks * 32 + lg * 8);
        #pragma unroll
        for (int mt = 0; mt < 4; ++mt)
            #pragma unroll
            for (int nt = 0; nt < 4; ++nt)
                acc[mt][nt] = MFMA16(af[mt], bf[nt], acc[mt][nt]);
    }

    #pragma unroll
    for (int mt = 0; mt < 4; ++mt) {
        #pragma unroll
        for (int nt = 0; nt < 4; ++nt) {
            const int nbase = n0 + wno + nt * 16;   // multiple of 16
            const int rrow  = nbase >> 4;
            #pragma unroll
            for (int r = 0; r < 4; ++r) {
                const int i = i0 + wio + mt * 16 + lg * 4 + r;
                const size_t gidx = ((size_t)rrow * L + i) * D + h * HD + lr;
                out[gidx] = min_[gidx] + acc[mt][nt][r];
            }
        }
    }
}

// ---------------------------------------------------------------------------
// Kernel 5: fused LN3 + FFN (MFMA) + residual, in place on out. 32 rows/block.
// ---------------------------------------------------------------------------
__global__ void k_ffn(const float* __restrict__ g3,
                      const float* __restrict__ bt3,
                      const unsigned short* __restrict__ w1t,
                      const float* __restrict__ ffb1,
                      const unsigned short* __restrict__ w2t,
                      const float* __restrict__ ffb2,
                      float* __restrict__ out) {
    __shared__ unsigned short resN[32][136];
    __shared__ unsigned short hid[32][520];
    const int tid = threadIdx.x;
    const size_t row0 = (size_t)blockIdx.x * 32;

    // Phase A: LN3, 8 threads per row x 16 channels
    {
        const int rr = tid >> 3, part = tid & 7;
        const float* src = out + (row0 + rr) * D + part * 16;
        float v[16];
        float s = 0.f, sq = 0.f;
        #pragma unroll
        for (int q = 0; q < 4; ++q) {
            const float4 a = ((const float4*)src)[q];
            v[q*4+0] = a.x; v[q*4+1] = a.y; v[q*4+2] = a.z; v[q*4+3] = a.w;
            s  += a.x + a.y + a.z + a.w;
            sq += a.x*a.x + a.y*a.y + a.z*a.z + a.w*a.w;
        }
        s  += __shfl_xor(s, 1);  s  += __shfl_xor(s, 2);  s  += __shfl_xor(s, 4);
        sq += __shfl_xor(sq, 1); sq += __shfl_xor(sq, 2); sq += __shfl_xor(sq, 4);
        const float mean = s * (1.0f / D);
        const float rstd = rsqrtf(sq * (1.0f / D) - mean * mean + 1e-5f);
        #pragma unroll
        for (int q = 0; q < 4; ++q) {
            const int c = part * 16 + q * 4;
            ushort4 pk;
            pk.x = f2bf((v[q*4+0] - mean) * rstd * g3[c+0] + bt3[c+0]);
            pk.y = f2bf((v[q*4+1] - mean) * rstd * g3[c+1] + bt3[c+1]);
            pk.z = f2bf((v[q*4+2] - mean) * rstd * g3[c+2] + bt3[c+2]);
            pk.w = f2bf((v[q*4+3] - mean) * rstd * g3[c+3] + bt3[c+3]);
            *(ushort4*)(&resN[rr][c]) = pk;
        }
    }
    __syncthreads();

    const int wv = tid >> 6, lane = tid & 63;
    const int lr = lane & 15, lg = lane >> 4;

    // Phase B: hid = relu(resN @ w1t^T + ffb1); wave handles 128 hidden cols
    {
        f32x4 acc[2][8];
        #pragma unroll
        for (int m = 0; m < 2; ++m)
            #pragma unroll
            for (int n = 0; n < 8; ++n) acc[m][n] = (f32x4){0.f, 0.f, 0.f, 0.f};

        #pragma unroll
        for (int ks = 0; ks < 4; ++ks) {
            bf16x8 a0 = *(const bf16x8*)(&resN[lr][ks * 32 + lg * 8]);
            bf16x8 a1 = *(const bf16x8*)(&resN[16 + lr][ks * 32 + lg * 8]);
            #pragma unroll
            for (int nt = 0; nt < 8; ++nt) {
                const unsigned short* bp = w1t + (size_t)(wv * 128 + nt * 16 + lr) * D + ks * 32 + lg * 8;
                bf16x8 b = *(const bf16x8*)bp;
                acc[0][nt] = MFMA16(a0, b, acc[0][nt]);
                acc[1][nt] = MFMA16(a1, b, acc[1][nt]);
            }
        }
        #pragma unroll
        for (int m = 0; m < 2; ++m) {
            #pragma unroll
            for (int nt = 0; nt < 8; ++nt) {
                const int colg = wv * 128 + nt * 16 + lr;
                const float bb = ffb1[colg];
                #pragma unroll
                for (int r = 0; r < 4; ++r) {
                    hid[m * 16 + lg * 4 + r][colg] = f2bf(fmaxf(acc[m][nt][r] + bb, 0.f));
                }
            }
        }
    }
    __syncthreads();

    // Phase C: final = hid @ w2t^T + ffb2 + residual; wave handles 32 cols
    {
        f32x4 acc2[2][2];
        #pragma unroll
        for (int m = 0; m < 2; ++m)
            #pragma unroll
            for (int n = 0; n < 2; ++n) acc2[m][n] = (f32x4){0.f, 0.f, 0.f, 0.f};

        #pragma unroll
        for (int ks = 0; ks < 16; ++ks) {
            bf16x8 a0 = *(const bf16x8*)(&hid[lr][ks * 32 + lg * 8]);
            bf16x8 a1 = *(const bf16x8*)(&hid[16 + lr][ks * 32 + lg * 8]);
            #pragma unroll
            for (int nt = 0; nt < 2; ++nt) {
                const unsigned short* bp = w2t + (size_t)(wv * 32 + nt * 16 + lr) * FF + ks * 32 + lg * 8;
                bf16x8 b = *(const bf16x8*)bp;
                acc2[0][nt] = MFMA16(a0, b, acc2[0][nt]);
                acc2[1][nt] = MFMA16(a1, b, acc2[1][nt]);
            }
        }
        #pragma unroll
        for (int m = 0; m < 2; ++m) {
            #pragma unroll
            for (int nt = 0; nt < 2; ++nt) {
                const int n = wv * 32 + nt * 16 + lr;
                const float bb = ffb2[n];
                #pragma unroll
                for (int r = 0; r < 4; ++r) {
                    const size_t gi = (row0 + m * 16 + lg * 4 + r) * (size_t)D + n;
                    out[gi] = out[gi] + acc2[m][nt][r] + bb;
                }
            }
        }
    }
}

// ---------------------------------------------------------------------------
extern "C" void kernel_launch(void* const* d_in, const int* in_sizes, int n_in,
                              void* d_out, int out_size, void* d_ws, size_t ws_size,
                              hipStream_t stream) {
    const float* x     = (const float*)d_in[0];
    const float* m     = (const float*)d_in[1];
    const float* ln1_g = (const float*)d_in[2];
    const float* ln1_b = (const float*)d_in[3];
    const float* ln2_g = (const float*)d_in[4];
    const float* ln2_b = (const float*)d_in[5];
    const float* ln3_g = (const float*)d_in[6];
    const float* ln3_b = (const float*)d_in[7];
    const float* w1    = (const float*)d_in[8];
    const float* b1    = (const float*)d_in[9];
    const float* w2    = (const float*)d_in[10];
    const float* b2    = (const float*)d_in[11];
    const float* ffw1  = (const float*)d_in[12];
    const float* ffb1  = (const float*)d_in[13];
    const float* ffw2  = (const float*)d_in[14];
    const float* ffb2  = (const float*)d_in[15];

    float* out = (float*)d_out;

    float*          logits = (float*)d_ws;                                   // 4.72 MB
    unsigned short* attnT  = (unsigned short*)(logits + (size_t)L * L * NH); // 2.36 MB
    unsigned short* VtT    = attnT + (size_t)NH * L * L;                     // 3.15 MB
    unsigned short* w1t    = VtT + (size_t)R * HD * L;                       // 128 KB
    unsigned short* w2t    = w1t + (size_t)FF * D;                           // 128 KB
    unsigned short* w1p    = w2t + (size_t)D * FF;                           // 4 KB
    unsigned short* w2p    = w1p + (size_t)16 * D;                           // 4 KB

    k_prep<<<(FF * D) / 256, 256, 0, stream>>>(w1, w2, ffw1, ffw2, w1p, w2p, w1t, w2t);
    k_pair_logits<<<(L * L) / 64, 256, 0, stream>>>(x, ln1_g, ln1_b, w1p, b1, logits);
    k_softmax<<<(L * NH) / 4, 256, 0, stream>>>(logits, attnT);

    dim3 g3(R, L / 128);
    k_values<<<g3, 256, 0, stream>>>(m, ln2_g, ln2_b, w2p, b2, VtT);

    dim3 g4(L / 128, (R * HD) / 128, NH);
    k_attn_out<<<g4, 256, 0, stream>>>(attnT, VtT, m, out);

    k_ffn<<<(R * L) / 32, 256, 0, stream>>>(ln3_g, ln3_b, w1t, ffb1, w2t, ffb2, out);
}

// Round 4
// 213.780 us; speedup vs baseline: 4.0891x; 1.0861x over previous
//
#include <hip/hip_runtime.h>

typedef __attribute__((ext_vector_type(8))) short bf16x8;
typedef __attribute__((ext_vector_type(4))) float f32x4;

constexpr int L  = 384;
constexpr int R  = 256;
constexpr int D  = 128;
constexpr int NH = 8;
constexpr int HD = 16;
constexpr int FF = 512;

#define MFMA16(a, b, c) __builtin_amdgcn_mfma_f32_16x16x32_bf16((a), (b), (c), 0, 0, 0)

__device__ inline unsigned short f2bf(float f) {
    unsigned u = __builtin_bit_cast(unsigned, f);
    u += 0x7fffu + ((u >> 16) & 1u);          // round-to-nearest-even
    return (unsigned short)(u >> 16);
}

// triangular row from linear upper-tri index q (i<=j), L=384: off(i)=i*(769-i)/2
__device__ inline int tri_row(int q) {
    int i = (int)((769.0f - sqrtf((float)(591361 - 8 * q))) * 0.5f);
    while ((i + 1) * (769 - (i + 1)) / 2 <= q) ++i;
    while (i * (769 - i) / 2 > q) --i;
    return i;
}

// ---------------------------------------------------------------------------
// Prep: bf16-transposed weight copies in workspace.
// ---------------------------------------------------------------------------
__global__ void k_prep(const float* __restrict__ w1,
                       const float* __restrict__ w2,
                       const float* __restrict__ ffw1,
                       const float* __restrict__ ffw2,
                       unsigned short* __restrict__ w1p,
                       unsigned short* __restrict__ w2p,
                       unsigned short* __restrict__ w1t,
                       unsigned short* __restrict__ w2t) {
    const int idx = blockIdx.x * 256 + threadIdx.x;   // 65536 threads
    { const int n = idx >> 7, k = idx & 127; w1t[idx] = f2bf(ffw1[(size_t)k * FF + n]); }
    { const int n = idx >> 9, k = idx & 511; w2t[idx] = f2bf(ffw2[(size_t)k * D + n]); }
    if (idx < 16 * D) {
        const int n = idx >> 7, k = idx & 127;
        w1p[idx] = (n < NH) ? f2bf(w1[(size_t)k * NH + n]) : (unsigned short)0;
        w2p[idx] = f2bf(w2[(size_t)k * HD + n]);
    }
}

// ---------------------------------------------------------------------------
// Kernel 1: symmetrize + LN1 + logits via MFMA, upper triangle only
// (result is symmetric in (i,j)); 64 tri-pairs per block, mirrored writes.
// ---------------------------------------------------------------------------
__global__ void k_pair_logits(const float* __restrict__ x,
                              const float* __restrict__ g,
                              const float* __restrict__ bt,
                              const unsigned short* __restrict__ w1p,
                              const float* __restrict__ b1,
                              float* __restrict__ logits) {
    __shared__ unsigned short nrm[64][136];
    __shared__ int ij[64];
    const int tid = threadIdx.x;
    const int q0 = blockIdx.x * 64;

    // Phase A: LN over 128 channels; 4 threads per pair, 32 channels each
    {
        const int pr = tid >> 2, part = tid & 3;
        const int q = q0 + pr;
        const int i = tri_row(q);
        const int j = i + (q - i * (769 - i) / 2);
        if (part == 0) ij[pr] = (i << 16) | j;
        const float* xa = x + ((size_t)i * L + j) * D + part * 32;
        const float* xb = x + ((size_t)j * L + i) * D + part * 32;
        float v[32];
        float s = 0.f, sq = 0.f;
        #pragma unroll
        for (int q8 = 0; q8 < 8; ++q8) {
            const float4 a = ((const float4*)xa)[q8];
            const float4 b = ((const float4*)xb)[q8];
            const float t0 = 0.5f * (a.x + b.x), t1 = 0.5f * (a.y + b.y);
            const float t2 = 0.5f * (a.z + b.z), t3 = 0.5f * (a.w + b.w);
            v[q8*4+0] = t0; v[q8*4+1] = t1; v[q8*4+2] = t2; v[q8*4+3] = t3;
            s  += t0 + t1 + t2 + t3;
            sq += t0*t0 + t1*t1 + t2*t2 + t3*t3;
        }
        s  += __shfl_xor(s, 1);  s  += __shfl_xor(s, 2);
        sq += __shfl_xor(sq, 1); sq += __shfl_xor(sq, 2);
        const float mean = s * (1.0f / D);
        const float rstd = rsqrtf(sq * (1.0f / D) - mean * mean + 1e-5f);
        #pragma unroll
        for (int q8 = 0; q8 < 8; ++q8) {
            const int c = part * 32 + q8 * 4;
            ushort4 pk;
            pk.x = f2bf((v[q8*4+0] - mean) * rstd * g[c+0] + bt[c+0]);
            pk.y = f2bf((v[q8*4+1] - mean) * rstd * g[c+1] + bt[c+1]);
            pk.z = f2bf((v[q8*4+2] - mean) * rstd * g[c+2] + bt[c+2]);
            pk.w = f2bf((v[q8*4+3] - mean) * rstd * g[c+3] + bt[c+3]);
            *(ushort4*)(&nrm[pr][c]) = pk;
        }
    }
    __syncthreads();

    // Phase B: logits = nrm @ w1 via MFMA; mirrored scatter to (i,j) and (j,i)
    {
        const int wv = tid >> 6, lane = tid & 63;
        const int lr = lane & 15, lg = lane >> 4;
        f32x4 acc = {0.f, 0.f, 0.f, 0.f};
        #pragma unroll
        for (int ks = 0; ks < 4; ++ks) {
            bf16x8 a = *(const bf16x8*)(&nrm[wv * 16 + lr][ks * 32 + lg * 8]);
            bf16x8 b = *(const bf16x8*)(w1p + (size_t)lr * D + ks * 32 + lg * 8);
            acc = MFMA16(a, b, acc);
        }
        if (lr < NH) {
            #pragma unroll
            for (int r = 0; r < 4; ++r) {
                const int pl = wv * 16 + lg * 4 + r;
                const int pij = ij[pl];
                const int pi = pij >> 16, pj = pij & 0xffff;
                const float val = acc[r] + b1[lr];
                logits[((size_t)pi * L + pj) * NH + lr] = val;
                logits[((size_t)pj * L + pi) * NH + lr] = val;
            }
        }
    }
}

// ---------------------------------------------------------------------------
// Kernel 2: softmax over j for each (i,h); logits f32 -> attnT bf16 [h][i][j]
// ---------------------------------------------------------------------------
__global__ void k_softmax(const float* __restrict__ logits,
                          unsigned short* __restrict__ attnT) {
    const int wave = blockIdx.x * 4 + (threadIdx.x >> 6);
    const int lane = threadIdx.x & 63;
    const int i = wave >> 3, h = wave & 7;

    float v[6];
    float mx = -1e30f;
    #pragma unroll
    for (int t = 0; t < 6; ++t) {
        const int j = lane + t * 64;
        v[t] = logits[((size_t)i * L + j) * NH + h];
        mx = fmaxf(mx, v[t]);
    }
    #pragma unroll
    for (int msk = 32; msk; msk >>= 1) mx = fmaxf(mx, __shfl_xor(mx, msk));

    float s = 0.0f;
    #pragma unroll
    for (int t = 0; t < 6; ++t) { v[t] = __expf(v[t] - mx); s += v[t]; }
    #pragma unroll
    for (int msk = 32; msk; msk >>= 1) s += __shfl_xor(s, msk);
    const float inv = 1.0f / s;

    #pragma unroll
    for (int t = 0; t < 6; ++t) {
        const int j = lane + t * 64;
        attnT[((size_t)h * L + i) * L + j] = f2bf(v[t] * inv);
    }
}

// ---------------------------------------------------------------------------
// Kernel 3: values = LN2(m) @ w2 + b2 -> VtT bf16 [n = r*16+d][j]
// ---------------------------------------------------------------------------
__global__ void k_values(const float* __restrict__ min_,
                         const float* __restrict__ g,
                         const float* __restrict__ bt,
                         const unsigned short* __restrict__ w2p,
                         const float* __restrict__ b2,
                         unsigned short* __restrict__ VtT) {
    __shared__ unsigned short nrm[128][136];
    const int tid = threadIdx.x;
    const int r  = blockIdx.x;
    const int j0 = blockIdx.y * 128;

    #pragma unroll
    for (int half = 0; half < 2; ++half) {
        const int row  = half * 64 + (tid >> 2);
        const int part = tid & 3;
        const float* src = min_ + ((size_t)r * L + j0 + row) * D + part * 32;
        float v[32];
        float s = 0.f, sq = 0.f;
        #pragma unroll
        for (int q = 0; q < 8; ++q) {
            const float4 a = ((const float4*)src)[q];
            v[q*4+0] = a.x; v[q*4+1] = a.y; v[q*4+2] = a.z; v[q*4+3] = a.w;
            s  += a.x + a.y + a.z + a.w;
            sq += a.x*a.x + a.y*a.y + a.z*a.z + a.w*a.w;
        }
        s  += __shfl_xor(s, 1);  s  += __shfl_xor(s, 2);
        sq += __shfl_xor(sq, 1); sq += __shfl_xor(sq, 2);
        const float mean = s * (1.0f / D);
        const float rstd = rsqrtf(sq * (1.0f / D) - mean * mean + 1e-5f);
        #pragma unroll
        for (int q = 0; q < 8; ++q) {
            const int c = part * 32 + q * 4;
            ushort4 pk;
            pk.x = f2bf((v[q*4+0] - mean) * rstd * g[c+0] + bt[c+0]);
            pk.y = f2bf((v[q*4+1] - mean) * rstd * g[c+1] + bt[c+1]);
            pk.z = f2bf((v[q*4+2] - mean) * rstd * g[c+2] + bt[c+2]);
            pk.w = f2bf((v[q*4+3] - mean) * rstd * g[c+3] + bt[c+3]);
            *(ushort4*)(&nrm[row][c]) = pk;
        }
    }
    __syncthreads();

    {
        const int wv = tid >> 6, lane = tid & 63;
        const int lr = lane & 15, lg = lane >> 4;
        f32x4 acc[2];
        acc[0] = (f32x4){0.f, 0.f, 0.f, 0.f};
        acc[1] = (f32x4){0.f, 0.f, 0.f, 0.f};
        #pragma unroll
        for (int ks = 0; ks < 4; ++ks) {
            bf16x8 b = *(const bf16x8*)(w2p + (size_t)lr * D + ks * 32 + lg * 8);
            #pragma unroll
            for (int mt = 0; mt < 2; ++mt) {
                bf16x8 a = *(const bf16x8*)(&nrm[wv * 32 + mt * 16 + lr][ks * 32 + lg * 8]);
                acc[mt] = MFMA16(a, b, acc[mt]);
            }
        }
        const float bb = b2[lr];
        #pragma unroll
        for (int mt = 0; mt < 2; ++mt) {
            ushort4 pk;
            pk.x = f2bf(acc[mt][0] + bb);
            pk.y = f2bf(acc[mt][1] + bb);
            pk.z = f2bf(acc[mt][2] + bb);
            pk.w = f2bf(acc[mt][3] + bb);
            *(ushort4*)(VtT + (size_t)(r * HD + lr) * L + j0 + wv * 32 + mt * 16 + lg * 4) = pk;
        }
    }
}

// ---------------------------------------------------------------------------
// Kernel 4: einsum via MFMA. Per head: C[i,n] = sum_j attnT[h][i][j]*VtT[n][j]
// ---------------------------------------------------------------------------
__global__ void k_attn_out(const unsigned short* __restrict__ attnT,
                           const unsigned short* __restrict__ VtT,
                           const float* __restrict__ min_,
                           float* __restrict__ out) {
    const int h  = blockIdx.z;
    const int i0 = blockIdx.x * 128;
    const int n0 = blockIdx.y * 128;
    const int tid = threadIdx.x, wv = tid >> 6, lane = tid & 63;
    const int lr = lane & 15, lg = lane >> 4;
    const int wio = (wv >> 1) * 64, wno = (wv & 1) * 64;
    const unsigned short* Abase = attnT + (size_t)h * L * L;

    f32x4 acc[4][4];
    #pragma unroll
    for (int a = 0; a < 4; ++a)
        #pragma unroll
        for (int b = 0; b < 4; ++b) acc[a][b] = (f32x4){0.f, 0.f, 0.f, 0.f};

    for (int ks = 0; ks < 12; ++ks) {
        bf16x8 af[4], bf[4];
        #pragma unroll
        for (int mt = 0; mt < 4; ++mt)
            af[mt] = *(const bf16x8*)(Abase + (size_t)(i0 + wio + mt * 16 + lr) * L + ks * 32 + lg * 8);
        #pragma unroll
        for (int nt = 0; nt < 4; ++nt)
            bf[nt] = *(const bf16x8*)(VtT + (size_t)(n0 + wno + nt * 16 + lr) * L + ks * 32 + lg * 8);
        #pragma unroll
        for (int mt = 0; mt < 4; ++mt)
            #pragma unroll
            for (int nt = 0; nt < 4; ++nt)
                acc[mt][nt] = MFMA16(af[mt], bf[nt], acc[mt][nt]);
    }

    #pragma unroll
    for (int mt = 0; mt < 4; ++mt) {
        #pragma unroll
        for (int nt = 0; nt < 4; ++nt) {
            const int nbase = n0 + wno + nt * 16;
            const int rrow  = nbase >> 4;
            #pragma unroll
            for (int r = 0; r < 4; ++r) {
                const int i = i0 + wio + mt * 16 + lg * 4 + r;
                const size_t gidx = ((size_t)rrow * L + i) * D + h * HD + lr;
                out[gidx] = min_[gidx] + acc[mt][nt][r];
            }
        }
    }
}

// ---------------------------------------------------------------------------
// Kernel 5: fused LN3 + FFN (MFMA) + residual. 512 threads, 32 rows/block.
// LDS 41 KB -> 3 blocks/CU x 8 waves = 24 waves/CU (vs 12 before).
// ---------------------------------------------------------------------------
__global__ __launch_bounds__(512, 6) void k_ffn(
                      const float* __restrict__ g3,
                      const float* __restrict__ bt3,
                      const unsigned short* __restrict__ w1t,
                      const float* __restrict__ ffb1,
                      const unsigned short* __restrict__ w2t,
                      const float* __restrict__ ffb2,
                      float* __restrict__ out) {
    __shared__ unsigned short resN[32][136];
    __shared__ unsigned short hid[32][520];
    const int tid = threadIdx.x;
    const size_t row0 = (size_t)blockIdx.x * 32;

    // Phase A: LN3, 16 threads per row x 8 channels
    {
        const int rr = tid >> 4, part = tid & 15;
        const float* src = out + (row0 + rr) * D + part * 8;
        const float4 a0 = ((const float4*)src)[0];
        const float4 a1 = ((const float4*)src)[1];
        float s  = a0.x + a0.y + a0.z + a0.w + a1.x + a1.y + a1.z + a1.w;
        float sq = a0.x*a0.x + a0.y*a0.y + a0.z*a0.z + a0.w*a0.w
                 + a1.x*a1.x + a1.y*a1.y + a1.z*a1.z + a1.w*a1.w;
        s  += __shfl_xor(s, 1);  s  += __shfl_xor(s, 2);
        s  += __shfl_xor(s, 4);  s  += __shfl_xor(s, 8);
        sq += __shfl_xor(sq, 1); sq += __shfl_xor(sq, 2);
        sq += __shfl_xor(sq, 4); sq += __shfl_xor(sq, 8);
        const float mean = s * (1.0f / D);
        const float rstd = rsqrtf(sq * (1.0f / D) - mean * mean + 1e-5f);
        const int c = part * 8;
        ushort4 p0, p1;
        p0.x = f2bf((a0.x - mean) * rstd * g3[c+0] + bt3[c+0]);
        p0.y = f2bf((a0.y - mean) * rstd * g3[c+1] + bt3[c+1]);
        p0.z = f2bf((a0.z - mean) * rstd * g3[c+2] + bt3[c+2]);
        p0.w = f2bf((a0.w - mean) * rstd * g3[c+3] + bt3[c+3]);
        p1.x = f2bf((a1.x - mean) * rstd * g3[c+4] + bt3[c+4]);
        p1.y = f2bf((a1.y - mean) * rstd * g3[c+5] + bt3[c+5]);
        p1.z = f2bf((a1.z - mean) * rstd * g3[c+6] + bt3[c+6]);
        p1.w = f2bf((a1.w - mean) * rstd * g3[c+7] + bt3[c+7]);
        *(ushort4*)(&resN[rr][c])     = p0;
        *(ushort4*)(&resN[rr][c + 4]) = p1;
    }
    __syncthreads();

    const int wv = tid >> 6, lane = tid & 63;
    const int lr = lane & 15, lg = lane >> 4;

    // Phase B: hid = relu(resN @ w1t^T + ffb1); wave handles 64 hidden cols
    {
        f32x4 acc[2][4];
        #pragma unroll
        for (int m = 0; m < 2; ++m)
            #pragma unroll
            for (int n = 0; n < 4; ++n) acc[m][n] = (f32x4){0.f, 0.f, 0.f, 0.f};

        #pragma unroll
        for (int ks = 0; ks < 4; ++ks) {
            bf16x8 a0 = *(const bf16x8*)(&resN[lr][ks * 32 + lg * 8]);
            bf16x8 a1 = *(const bf16x8*)(&resN[16 + lr][ks * 32 + lg * 8]);
            #pragma unroll
            for (int nt = 0; nt < 4; ++nt) {
                const unsigned short* bp = w1t + (size_t)(wv * 64 + nt * 16 + lr) * D + ks * 32 + lg * 8;
                bf16x8 b = *(const bf16x8*)bp;
                acc[0][nt] = MFMA16(a0, b, acc[0][nt]);
                acc[1][nt] = MFMA16(a1, b, acc[1][nt]);
            }
        }
        #pragma unroll
        for (int m = 0; m < 2; ++m) {
            #pragma unroll
            for (int nt = 0; nt < 4; ++nt) {
                const int colg = wv * 64 + nt * 16 + lr;
                const float bb = ffb1[colg];
                #pragma unroll
                for (int r = 0; r < 4; ++r) {
                    hid[m * 16 + lg * 4 + r][colg] = f2bf(fmaxf(acc[m][nt][r] + bb, 0.f));
                }
            }
        }
    }
    __syncthreads();

    // Phase C: final = hid @ w2t^T + ffb2 + residual; wave handles 16 cols
    {
        f32x4 acc2[2];
        acc2[0] = (f32x4){0.f, 0.f, 0.f, 0.f};
        acc2[1] = (f32x4){0.f, 0.f, 0.f, 0.f};

        #pragma unroll
        for (int ks = 0; ks < 16; ++ks) {
            bf16x8 a0 = *(const bf16x8*)(&hid[lr][ks * 32 + lg * 8]);
            bf16x8 a1 = *(const bf16x8*)(&hid[16 + lr][ks * 32 + lg * 8]);
            const unsigned short* bp = w2t + (size_t)(wv * 16 + lr) * FF + ks * 32 + lg * 8;
            bf16x8 b = *(const bf16x8*)bp;
            acc2[0] = MFMA16(a0, b, acc2[0]);
            acc2[1] = MFMA16(a1, b, acc2[1]);
        }
        const int n = wv * 16 + lr;
        const float bb = ffb2[n];
        #pragma unroll
        for (int m = 0; m < 2; ++m) {
            #pragma unroll
            for (int r = 0; r < 4; ++r) {
                const size_t gi = (row0 + m * 16 + lg * 4 + r) * (size_t)D + n;
                out[gi] = out[gi] + acc2[m][r] + bb;
            }
        }
    }
}

// ---------------------------------------------------------------------------
extern "C" void kernel_launch(void* const* d_in, const int* in_sizes, int n_in,
                              void* d_out, int out_size, void* d_ws, size_t ws_size,
                              hipStream_t stream) {
    const float* x     = (const float*)d_in[0];
    const float* m     = (const float*)d_in[1];
    const float* ln1_g = (const float*)d_in[2];
    const float* ln1_b = (const float*)d_in[3];
    const float* ln2_g = (const float*)d_in[4];
    const float* ln2_b = (const float*)d_in[5];
    const float* ln3_g = (const float*)d_in[6];
    const float* ln3_b = (const float*)d_in[7];
    const float* w1    = (const float*)d_in[8];
    const float* b1    = (const float*)d_in[9];
    const float* w2    = (const float*)d_in[10];
    const float* b2    = (const float*)d_in[11];
    const float* ffw1  = (const float*)d_in[12];
    const float* ffb1  = (const float*)d_in[13];
    const float* ffw2  = (const float*)d_in[14];
    const float* ffb2  = (const float*)d_in[15];

    float* out = (float*)d_out;

    float*          logits = (float*)d_ws;                                   // 4.72 MB
    unsigned short* attnT  = (unsigned short*)(logits + (size_t)L * L * NH); // 2.36 MB
    unsigned short* VtT    = attnT + (size_t)NH * L * L;                     // 3.15 MB
    unsigned short* w1t    = VtT + (size_t)R * HD * L;                       // 128 KB
    unsigned short* w2t    = w1t + (size_t)FF * D;                           // 128 KB
    unsigned short* w1p    = w2t + (size_t)D * FF;                           // 4 KB
    unsigned short* w2p    = w1p + (size_t)16 * D;                           // 4 KB

    k_prep<<<(FF * D) / 256, 256, 0, stream>>>(w1, w2, ffw1, ffw2, w1p, w2p, w1t, w2t);

    // upper-triangle pair count: 384*385/2 = 73920 -> 1155 blocks of 64
    k_pair_logits<<<1155, 256, 0, stream>>>(x, ln1_g, ln1_b, w1p, b1, logits);
    k_softmax<<<(L * NH) / 4, 256, 0, stream>>>(logits, attnT);

    dim3 g3(R, L / 128);
    k_values<<<g3, 256, 0, stream>>>(m, ln2_g, ln2_b, w2p, b2, VtT);

    dim3 g4(L / 128, (R * HD) / 128, NH);
    k_attn_out<<<g4, 256, 0, stream>>>(attnT, VtT, m, out);

    k_ffn<<<(R * L) / 32, 512, 0, stream>>>(ln3_g, ln3_b, w1t, ffb1, w2t, ffb2, out);
}